// Round 5
// baseline (551.273 us; speedup 1.0000x reference)
//
#include <hip/hip_runtime.h>
#include <hip/hip_bf16.h>

typedef __hip_bfloat16 bf16;
typedef __attribute__((ext_vector_type(8))) short short8;
typedef __attribute__((ext_vector_type(4))) float f32x4;
typedef __attribute__((ext_vector_type(8))) __bf16 bf16x8;

#define NB 32768
#define DD 768
#define AA 17
#define HH 128

__device__ __forceinline__ float bs2f(short s){
  unsigned int u = ((unsigned int)(unsigned short)s) << 16;
  return __builtin_bit_cast(float, u);
}
__device__ __forceinline__ short f2bs(float f){
  bf16 h = __float2bfloat16(f);
  return __builtin_bit_cast(short, h);
}
__device__ __forceinline__ f32x4 mfma16(short8 a, short8 b, f32x4 c){
  return __builtin_amdgcn_mfma_f32_16x16x32_bf16(
      __builtin_bit_cast(bf16x8, a), __builtin_bit_cast(bf16x8, b), c, 0, 0, 0);
}

// load 8 consecutive elements starting at elem_off; convert to bf16 if F32
template<int F32>
__device__ __forceinline__ short8 ldchunk(const void* base, long elem_off){
  if (F32){
    const float4* p = (const float4*)((const float*)base + elem_off);
    float4 x = p[0], y = p[1];
    short8 r;
    r[0]=f2bs(x.x); r[1]=f2bs(x.y); r[2]=f2bs(x.z); r[3]=f2bs(x.w);
    r[4]=f2bs(y.x); r[5]=f2bs(y.y); r[6]=f2bs(y.z); r[7]=f2bs(y.w);
    return r;
  } else {
    return *(const short8*)((const short*)base + elem_off);
  }
}

// ---------------- prep kernels (all inputs fp32) ----------------

__device__ __forceinline__ float blk_mean128(float v, float* tmp){
  int t = threadIdx.x;
  #pragma unroll
  for (int m = 32; m; m >>= 1) v += __shfl_xor(v, m);
  if ((t & 63) == 0) tmp[t >> 6] = v;
  __syncthreads();
  float r = (tmp[0] + tmp[1]) * (1.0f / 128.0f);
  __syncthreads();
  return r;
}

__global__ void prep1(const float* __restrict__ w_tok, const float* __restrict__ b_tok,
                      const float* __restrict__ pos, const float* __restrict__ g_auln,
                      float* __restrict__ ug, float* __restrict__ rg, float* __restrict__ coef){
  __shared__ float tmp[2];
  int h = threadIdx.x;
  float w = w_tok[h];
  float wbar = blk_mean128(w, tmp);
  float u = w - wbar;
  float g = g_auln[h];
  ug[h] = u * g;
  float muu = blk_mean128(u * u, tmp);
  if (h == 0) coef[0] = muu;
  float bt = b_tok[h];
  for (int a = 0; a < AA; ++a){
    float c = bt + pos[a * HH + h];
    float cbar = blk_mean128(c, tmp);
    float r = c - cbar;
    rg[a * HH + h] = r * g;
    float mur = blk_mean128(u * r, tmp);
    float mrr = blk_mean128(r * r, tmp);
    if (h == 0){ coef[1 + a] = mur; coef[18 + a] = mrr; }
  }
}

__global__ void prep2(const float* __restrict__ w_in, const float* __restrict__ b_in,
                      const float* __restrict__ b_auln, const float* __restrict__ b_q,
                      const float* __restrict__ ug, const float* __restrict__ rg,
                      float* __restrict__ Uk, float* __restrict__ Ck,
                      float* __restrict__ Uv, float* __restrict__ Cv,
                      float* __restrict__ Rk, float* __restrict__ Rv,
                      float* __restrict__ bqf){
  int hp = threadIdx.x, bid = blockIdx.x;
  const float* wqrow = w_in + (long)hp * HH;
  const float* wkrow = w_in + (long)(HH + hp) * HH;
  const float* wvrow = w_in + (long)(2 * HH + hp) * HH;
  if (bid < AA){
    int a = bid;
    float sk = 0.f, sv = 0.f;
    for (int t = 0; t < HH; ++t){
      float r = rg[a * HH + t];
      sk += r * wkrow[t];
      sv += r * wvrow[t];
    }
    Rk[a * HH + hp] = sk; Rv[a * HH + hp] = sv;
  } else if (bid == AA){
    float uk = 0.f, uv = 0.f, ck = 0.f, cv = 0.f;
    for (int t = 0; t < HH; ++t){
      float u = ug[t], ba = b_auln[t];
      float wk = wkrow[t], wv = wvrow[t];
      uk += u * wk; uv += u * wv; ck += ba * wk; cv += ba * wv;
    }
    Uk[hp] = uk; Uv[hp] = uv;
    Ck[hp] = ck + b_in[HH + hp];
    Cv[hp] = cv + b_in[2 * HH + hp];
  } else {
    float s = 0.f;
    for (int t = 0; t < HH; ++t) s += b_q[t] * wqrow[t];
    bqf[hp] = s + b_in[hp];
  }
}

// Wqf[h][j] = sum_t w_in[h][t] * w_q[t][j]  (bf16 out, internal)
__global__ void prep_wqf(const float* __restrict__ w_in, const float* __restrict__ w_q,
                         bf16* __restrict__ Wqf){
  __shared__ float wq[HH];
  int h = blockIdx.x, t = threadIdx.x;
  if (t < HH) wq[t] = w_in[(long)h * HH + t];
  __syncthreads();
  for (int j = t; j < DD; j += 256){
    float acc = 0.f;
    for (int k = 0; k < HH; ++k) acc += wq[k] * w_q[(long)k * DD + j];
    Wqf[(long)h * DD + j] = __float2bfloat16(acc);
  }
}

// ---------------- attention (folded K/V) ----------------
__global__ __launch_bounds__(128) void attn(
    const bf16* __restrict__ Q, const float* __restrict__ au, const float* __restrict__ coef,
    const float* __restrict__ Uk_, const float* __restrict__ Ck_,
    const float* __restrict__ Uv_, const float* __restrict__ Cv_,
    const float* __restrict__ Rk, const float* __restrict__ Rv,
    bf16* __restrict__ ctx){
  const int ROWS = 8;
  int h = threadIdx.x;
  long row0 = (long)blockIdx.x * ROWS;
  float Uk = Uk_[h], Ck = Ck_[h], Uv = Uv_[h], Cv = Cv_[h];
  float cA = coef[0];
  __shared__ float sa[ROWS * AA];
  for (int idx = h; idx < ROWS * AA; idx += 128)
    sa[idx] = au[row0 * AA + idx];
  __syncthreads();
  const float scale = 0.17677669529663689f; // 1/sqrt(32)
  for (int r = 0; r < ROWS; ++r){
    long row = row0 + r;
    float q = __bfloat162float(Q[row * HH + h]);
    float sc[AA], vv[AA];
    #pragma unroll
    for (int a = 0; a < AA; ++a){
      float s = sa[r * AA + a];
      float var = fmaf(s * s, cA, fmaf(2.f * s, coef[1 + a], coef[18 + a]));
      float rinv = rsqrtf(fmaxf(var, 0.f) + 1e-5f);
      float kk = fmaf(s, Uk, Rk[a * HH + h]) * rinv + Ck;
      vv[a]    = fmaf(s, Uv, Rv[a * HH + h]) * rinv + Cv;
      float p = q * kk;
      p += __shfl_xor(p, 16); p += __shfl_xor(p, 8); p += __shfl_xor(p, 4);
      p += __shfl_xor(p, 2);  p += __shfl_xor(p, 1);
      sc[a] = p * scale;
    }
    float mx = sc[0];
    #pragma unroll
    for (int a = 1; a < AA; ++a) mx = fmaxf(mx, sc[a]);
    float den = 0.f, cval = 0.f;
    #pragma unroll
    for (int a = 0; a < AA; ++a){
      float e = __expf(sc[a] - mx);
      den += e; cval += e * vv[a];
    }
    ctx[row * HH + h] = __float2bfloat16(cval / den);
  }
}

// ---------------- MFMA GEMM (A row-major MxK, B row-major NxK i.e. B^T) ----------------
// AF/BF template flags: 1 = fp32 source (convert during staging), 0 = bf16 source.
template<int AF, int BF>
__device__ __forceinline__ void gemm_phase(
    const void* __restrict__ A, long lda, int ks, int ko,
    const void* __restrict__ B, long ldb,
    long rowBase, int colBase,
    short* As, short* Bs, int tid, int w, int fr, int kq,
    f32x4 (&acc)[2][8])
{
  const int sr0 = tid >> 2,         sp0 = (tid & 3) * 8;
  const int sr1 = (tid + 256) >> 2, sp1 = (tid & 3) * 8;
  for (int kt = 0; kt < ks; ++kt){
    const long kA = (long)kt * 32;
    const long kB = ko + kA;
    short8 av0 = ldchunk<AF>(A, (rowBase + sr0) * lda + kA + sp0);
    short8 av1 = ldchunk<AF>(A, (rowBase + sr1) * lda + kA + sp1);
    short8 bv0 = ldchunk<BF>(B, (long)(colBase + sr0) * ldb + kB + sp0);
    short8 bv1 = ldchunk<BF>(B, (long)(colBase + sr1) * ldb + kB + sp1);
    __syncthreads();   // previous iteration's frag reads complete
    *(short8*)(As + sr0 * 40 + sp0) = av0;
    *(short8*)(As + sr1 * 40 + sp1) = av1;
    *(short8*)(Bs + sr0 * 40 + sp0) = bv0;
    *(short8*)(Bs + sr1 * 40 + sp1) = bv1;
    __syncthreads();   // tile visible
    const int ra0 = w * 32 + fr;
    short8 a0 = *(const short8*)(As + ra0 * 40 + kq * 8);
    short8 a1 = *(const short8*)(As + (ra0 + 16) * 40 + kq * 8);
    #pragma unroll
    for (int nt = 0; nt < 8; ++nt){
      short8 b = *(const short8*)(Bs + (nt * 16 + fr) * 40 + kq * 8);
      acc[0][nt] = mfma16(a0, b, acc[0][nt]);
      acc[1][nt] = mfma16(a1, b, acc[1][nt]);
    }
  }
}

// MODE 0: out = acc + bias                 -> bf16 (internal)
// MODE 1: out = LayerNorm(acc + bias)*g+b  -> bf16 (internal, full 128-col tile)
// MODE 2: out = acc + bias                 -> bf16 (internal)
// MODE 3: two K phases; sigmoid-gate mix with fp32 visual -> FP32 final output
template<int MODE, int A1F, int A2F, int BF>
__global__ __launch_bounds__(256) void gemm_bt(
    const void* __restrict__ A1, long lda1, int k1,
    const void* __restrict__ A2, long lda2, int k2, int koff2,
    const void* __restrict__ Bw, long ldb,
    const float* __restrict__ bias,
    const float* __restrict__ g_ln, const float* __restrict__ b_ln,
    const float* __restrict__ vf, const bf16* __restrict__ af,
    void* __restrict__ C, long ldc)
{
  __shared__ __align__(16) short smem[128 * 136]; // stage: As 128x40, Bs 128x40; epilogue: 128x136
  short* As = smem;
  short* Bs = smem + 5120;
  const int tid = threadIdx.x;
  const int w = tid >> 6, l = tid & 63;
  const long rowBase = (long)blockIdx.y * 128;
  const int colBase = blockIdx.x * 128;
  const int fr = l & 15;          // frag: C/D col within 16 / A row within 16
  const int kq = l >> 4;          // frag k-quad

  f32x4 acc[2][8];
  f32x4 zero = {0.f, 0.f, 0.f, 0.f};
  #pragma unroll
  for (int i = 0; i < 2; ++i)
    #pragma unroll
    for (int j = 0; j < 8; ++j) acc[i][j] = zero;

  gemm_phase<A1F, BF>(A1, lda1, k1, 0, Bw, ldb, rowBase, colBase, As, Bs, tid, w, fr, kq, acc);
  if (MODE == 3)
    gemm_phase<A2F, BF>(A2, lda2, k2, koff2, Bw, ldb, rowBase, colBase, As, Bs, tid, w, fr, kq, acc);
  __syncthreads();  // last frag reads done before epilogue overwrites LDS

  // ---- epilogue: frags -> LDS (bf16) ----
  short* ep = smem;
  if (MODE == 1){
    #pragma unroll
    for (int mt = 0; mt < 2; ++mt){
      #pragma unroll
      for (int r = 0; r < 4; ++r){
        float x[8]; float sm = 0.f, sq = 0.f;
        #pragma unroll
        for (int nt = 0; nt < 8; ++nt){
          const int col = colBase + nt * 16 + fr;
          x[nt] = acc[mt][nt][r] + bias[col];
          sm += x[nt]; sq += x[nt] * x[nt];
        }
        sm += __shfl_xor(sm, 1); sq += __shfl_xor(sq, 1);
        sm += __shfl_xor(sm, 2); sq += __shfl_xor(sq, 2);
        sm += __shfl_xor(sm, 4); sq += __shfl_xor(sq, 4);
        sm += __shfl_xor(sm, 8); sq += __shfl_xor(sq, 8);
        const float mu = sm * (1.f / 128.f);
        const float var = sq * (1.f / 128.f) - mu * mu;
        const float rinv = rsqrtf(fmaxf(var, 0.f) + 1e-5f);
        const int lrow = w * 32 + mt * 16 + kq * 4 + r;
        #pragma unroll
        for (int nt = 0; nt < 8; ++nt){
          const int col = colBase + nt * 16 + fr;
          float y = (x[nt] - mu) * rinv * g_ln[col] + b_ln[col];
          ep[lrow * 136 + nt * 16 + fr] = f2bs(y);
        }
      }
    }
  } else {
    #pragma unroll
    for (int nt = 0; nt < 8; ++nt){
      const int col = colBase + nt * 16 + fr;
      const float bv = bias[col];
      #pragma unroll
      for (int mt = 0; mt < 2; ++mt){
        const int lrow0 = w * 32 + mt * 16 + kq * 4;
        #pragma unroll
        for (int r = 0; r < 4; ++r)
          ep[(lrow0 + r) * 136 + nt * 16 + fr] = f2bs(acc[mt][nt][r] + bv);
      }
    }
  }
  __syncthreads();

  // ---- coalesced store pass (MODE3: gate+mix, FP32 output) ----
  #pragma unroll
  for (int it = 0; it < 8; ++it){
    const int cid = tid + it * 256;   // 2048 16B chunks in 128x128 tile
    const int rw = cid >> 4;
    const int cc = (cid & 15) * 8;
    const long gr = rowBase + rw;
    short8 vls = *(const short8*)(ep + rw * 136 + cc);
    if (MODE == 3){
      const float4* vp = (const float4*)(vf + gr * ldc + colBase + cc);
      const float4 v0 = vp[0], v1 = vp[1];
      const float vv[8] = {v0.x, v0.y, v0.z, v0.w, v1.x, v1.y, v1.z, v1.w};
      const short8 afv = *(const short8*)((const short*)af + gr * ldc + colBase + cc);
      float o[8];
      #pragma unroll
      for (int e = 0; e < 8; ++e){
        const float lin = bs2f(vls[e]);
        const float gate = 1.f / (1.f + __expf(-lin));
        o[e] = gate * bs2f(afv[e]) + (1.f - gate) * vv[e];
      }
      float* cp = (float*)C + gr * ldc + colBase + cc;
      *(float4*)cp       = {o[0], o[1], o[2], o[3]};
      *(float4*)(cp + 4) = {o[4], o[5], o[6], o[7]};
    } else {
      short* cp = (short*)C + gr * ldc + colBase + cc;
      *(short8*)cp = vls;
    }
  }
}

// ---------------- launch ----------------
// Output is FP32 (reference returns float32): d_out = 96 MB.
// Carve (all dead before final GEMM rewrites d_out): Q bf16 [0,8), ctx bf16 [8,16),
// aon bf16 [16,24), tables [24,~24.3) MB. d_ws: af bf16 48 MB only.
extern "C" void kernel_launch(void* const* d_in, const int* in_sizes, int n_in,
                              void* d_out, int out_size, void* d_ws, size_t ws_size,
                              hipStream_t stream){
  const float* visual = (const float*)d_in[0];
  const float* au     = (const float*)d_in[1];
  const float* w_tok  = (const float*)d_in[2];
  const float* b_tok  = (const float*)d_in[3];
  const float* pos    = (const float*)d_in[4];
  const float* g_auln = (const float*)d_in[5];
  const float* b_auln = (const float*)d_in[6];
  const float* w_q    = (const float*)d_in[7];
  const float* b_q    = (const float*)d_in[8];
  const float* w_in   = (const float*)d_in[9];
  const float* b_in   = (const float*)d_in[10];
  const float* w_ao   = (const float*)d_in[11];
  const float* b_ao   = (const float*)d_in[12];
  const float* g_aln  = (const float*)d_in[13];
  const float* b_aln  = (const float*)d_in[14];
  const float* w_out  = (const float*)d_in[15];
  const float* b_out  = (const float*)d_in[16];
  const float* w_gate = (const float*)d_in[17];
  const float* b_gate = (const float*)d_in[18];

  char* ob = (char*)d_out;
  bf16* Q   = (bf16*)(ob);                       // [0,8MB)
  bf16* ctx = (bf16*)(ob + ((size_t)8 << 20));   // [8,16MB)
  bf16* aon = (bf16*)(ob + ((size_t)16 << 20));  // [16,24MB)
  char* p = ob + ((size_t)24 << 20);             // tables ~0.3MB
  auto alloc = [&](size_t bytes){ char* r = p; p += (bytes + 255) & ~(size_t)255; return r; };
  bf16*  Wqf  = (bf16*) alloc((size_t)HH * DD * 2);
  float* bqf  = (float*)alloc(HH * 4);
  float* ug   = (float*)alloc(HH * 4);
  float* rg   = (float*)alloc(AA * HH * 4);
  float* coef = (float*)alloc(64 * 4);
  float* Uk   = (float*)alloc(HH * 4);
  float* Ck   = (float*)alloc(HH * 4);
  float* Uv   = (float*)alloc(HH * 4);
  float* Cv   = (float*)alloc(HH * 4);
  float* Rk   = (float*)alloc(AA * HH * 4);
  float* Rv   = (float*)alloc(AA * HH * 4);
  bf16*  af   = (bf16*)d_ws;                     // 48MB, the only ws use

  prep1<<<dim3(1), dim3(128), 0, stream>>>(w_tok, b_tok, pos, g_auln, ug, rg, coef);
  prep2<<<dim3(19), dim3(128), 0, stream>>>(w_in, b_in, b_auln, b_q, ug, rg, Uk, Ck, Uv, Cv, Rk, Rv, bqf);
  prep_wqf<<<dim3(128), dim3(256), 0, stream>>>(w_in, w_q, Wqf);

  // Q = visual @ Wqf^T + bqf     (A fp32, B bf16) -> bf16
  gemm_bt<0, 1, 0, 0><<<dim3(1, NB / 128), dim3(256), 0, stream>>>(
      visual, (long)DD, DD / 32,
      nullptr, 0L, 0, 0,
      Wqf, (long)DD,
      bqf, nullptr, nullptr, nullptr, nullptr,
      Q, (long)HH);

  attn<<<dim3(NB / 8), dim3(128), 0, stream>>>(Q, au, coef, Uk, Ck, Uv, Cv, Rk, Rv, ctx);

  // aon = LN(ctx @ w_ao^T + b_ao)   (A bf16, B fp32) -> bf16
  gemm_bt<1, 0, 0, 1><<<dim3(1, NB / 128), dim3(256), 0, stream>>>(
      ctx, (long)HH, HH / 32,
      nullptr, 0L, 0, 0,
      w_ao, (long)HH,
      b_ao, g_aln, b_aln, nullptr, nullptr,
      aon, (long)HH);

  // af = aon @ w_out^T + b_out      (A bf16, B fp32) -> bf16
  gemm_bt<2, 0, 0, 1><<<dim3(DD / 128, NB / 128), dim3(256), 0, stream>>>(
      aon, (long)HH, HH / 32,
      nullptr, 0L, 0, 0,
      w_out, (long)HH,
      b_out, nullptr, nullptr, nullptr, nullptr,
      af, (long)DD);

  // out = sigmoid(visual@Wg1^T + af@Wg2^T + b_gate) * af + (1-gate)*visual  -> FP32
  gemm_bt<3, 1, 0, 1><<<dim3(DD / 128, NB / 128), dim3(256), 0, stream>>>(
      visual, (long)DD, DD / 32,
      af, (long)DD, DD / 32, DD,
      w_gate, (long)(2 * DD),
      b_gate, nullptr, nullptr, visual, af,
      (float*)d_out, (long)DD);
}